// Round 14
// baseline (450.922 us; speedup 1.0000x reference)
//
#include <hip/hip_runtime.h>
#include <hip/hip_bf16.h>
#include <stdint.h>

// Problem constants (DGRUCell: DIM=512, BATCH=32768)
#define DIM      512
#define TWO_D    1024
#define FIVE_D   2560
#define BATCH    32768
#define LN_EPS   1e-5f
#define GATE_B   0.0f

typedef _Float16 f16x8 __attribute__((ext_vector_type(8)));
typedef _Float16 f16x4 __attribute__((ext_vector_type(4)));
typedef float    f32x4 __attribute__((ext_vector_type(4)));

// ---------------------------------------------------------------------------
// async global->LDS, 16B per lane. LDS dest = wave-uniform base + lane*16.
// ---------------------------------------------------------------------------
__device__ __forceinline__ void async_copy16(const void* g, void* l) {
  __builtin_amdgcn_global_load_lds(
      (const __attribute__((address_space(1))) uint32_t*)g,
      (__attribute__((address_space(3))) uint32_t*)l,
      16, 0, 0);
}

// Drain: all this wave's outstanding LDS reads must be DATA-complete before
// it may cross the following barrier (after which another wave's
// global_load_lds may overwrite the region).
#define LGKM_DRAIN() asm volatile("s_waitcnt lgkmcnt(0)" ::: "memory")

__device__ __forceinline__ uint32_t pack_pz(_Float16 p, _Float16 z) {
  return (uint32_t)__builtin_bit_cast(uint16_t, p) |
         ((uint32_t)__builtin_bit_cast(uint16_t, z) << 16);
}

// ---------------------------------------------------------------------------
// K0: fp32 -> fp16 weight conversion
// ---------------------------------------------------------------------------
__global__ __launch_bounds__(256)
void cvt_kernel(const float* __restrict__ s, _Float16* __restrict__ d, int n4) {
  int i = blockIdx.x * blockDim.x + threadIdx.x;
  if (i < n4) {
    float4 v = *(const float4*)(s + (size_t)i * 4);
    f16x4 o;
    o[0] = (_Float16)v.x; o[1] = (_Float16)v.y;
    o[2] = (_Float16)v.z; o[3] = (_Float16)v.w;
    *(f16x4*)&d[(size_t)i * 4] = o;
  }
}

// ---------------------------------------------------------------------------
// K1: LN1 over concat(x,h) -> inp fp16 [B, 1024]
// ---------------------------------------------------------------------------
__global__ __launch_bounds__(256)
void ln1_kernel(const float* __restrict__ x, const float* __restrict__ h,
                const float* __restrict__ w, const float* __restrict__ b,
                const float* __restrict__ mask, _Float16* __restrict__ inp)
{
  const int row = blockIdx.x;
  const int t   = threadIdx.x;
  const int col = t * 4;
  const float* src = (col < DIM) ? (x + (size_t)row * DIM + col)
                                 : (h + (size_t)row * DIM + (col - DIM));
  float4 v = *(const float4*)src;
  float s = v.x + v.y + v.z + v.w;
  float q = v.x * v.x + v.y * v.y + v.z * v.z + v.w * v.w;
#pragma unroll
  for (int o = 32; o > 0; o >>= 1) { s += __shfl_xor(s, o); q += __shfl_xor(q, o); }
  __shared__ float red[8];
  const int wid = t >> 6;
  if ((t & 63) == 0) { red[wid] = s; red[4 + wid] = q; }
  __syncthreads();
  s = red[0] + red[1] + red[2] + red[3];
  q = red[4] + red[5] + red[6] + red[7];
  const float mu   = s * (1.0f / TWO_D);
  const float rstd = rsqrtf(q * (1.0f / TWO_D) - mu * mu + LN_EPS);
  float vv[4] = { v.x, v.y, v.z, v.w };
  f16x4 o4;
#pragma unroll
  for (int i = 0; i < 4; ++i)
    o4[i] = (_Float16)(((vv[i] - mu) * rstd * w[col + i] + b[col + i]) * mask[col + i]);
  *(f16x4*)&inp[(size_t)row * TWO_D + col] = o4;
}

// ---------------------------------------------------------------------------
// K3: gate nonlinearities + LN2. Writes inp2 (fp16) and the packed
// {part16, z2} u32 per output element COALESCED into d_out (GEMM2 reads it
// and overwrites the same element with h_new — same-thread read-then-write).
// ---------------------------------------------------------------------------
__global__ __launch_bounds__(128)
void gate_ln2_kernel(const float* __restrict__ x, const float* __restrict__ h,
                     const _Float16* __restrict__ gates,
                     const float* __restrict__ w2, const float* __restrict__ b2,
                     const float* __restrict__ mask, _Float16* __restrict__ inp2,
                     uint32_t* __restrict__ pz_out)
{
  const int row = blockIdx.x;
  const int t   = threadIdx.x;
  const int j   = t * 4;
  const _Float16* g = gates + (size_t)row * FIVE_D;

  f16x4 g0 = *(const f16x4*)&g[j];
  f16x4 g1 = *(const f16x4*)&g[DIM + j];
  f16x4 g2 = *(const f16x4*)&g[2 * DIM + j];
  f16x4 g3 = *(const f16x4*)&g[3 * DIM + j];
  f16x4 g4 = *(const f16x4*)&g[4 * DIM + j];
  float4 xv = *(const float4*)(x + (size_t)row * DIM + j);
  float4 hv = *(const float4*)(h + (size_t)row * DIM + j);
  float xa[4] = { xv.x, xv.y, xv.z, xv.w };
  float ha[4] = { hv.x, hv.y, hv.z, hv.w };

  float xr[4], hr[4];
  uint4 pzv;
  uint32_t pza[4];
  float s = 0.f, q = 0.f;
#pragma unroll
  for (int i = 0; i < 4; ++i) {
    float rx = 1.0f / (1.0f + expf(-(float)g0[i]));
    float rh = 1.0f / (1.0f + expf(-(float)g1[i]));
    xr[i] = xa[i] * rx;
    hr[i] = ha[i] * rh;
    float a = (float)g2[i], bb = (float)g3[i], c = (float)g4[i] - GATE_B;
    float m = fmaxf(fmaxf(a, bb), c);
    float e0 = expf(a - m), e1 = expf(bb - m), e2 = expf(c - m);
    float inv = 1.0f / (e0 + e1 + e2);
    float z0 = e0 * inv, z1 = e1 * inv;
    pza[i] = pack_pz((_Float16)(xa[i] * z0 + ha[i] * z1), (_Float16)(e2 * inv));
    s += xr[i] + hr[i];
    q += xr[i] * xr[i] + hr[i] * hr[i];
  }
  pzv.x = pza[0]; pzv.y = pza[1]; pzv.z = pza[2]; pzv.w = pza[3];
  *(uint4*)&pz_out[(size_t)row * DIM + j] = pzv;

#pragma unroll
  for (int o = 32; o > 0; o >>= 1) { s += __shfl_xor(s, o); q += __shfl_xor(q, o); }
  __shared__ float red[4];
  const int wid = t >> 6;
  if ((t & 63) == 0) { red[wid] = s; red[2 + wid] = q; }
  __syncthreads();
  s = red[0] + red[1];
  q = red[2] + red[3];
  const float mu   = s * (1.0f / TWO_D);
  const float rstd = rsqrtf(q * (1.0f / TWO_D) - mu * mu + LN_EPS);

  f16x4 oA, oB;
#pragma unroll
  for (int i = 0; i < 4; ++i) {
    oA[i] = (_Float16)(((xr[i] - mu) * rstd * w2[j + i] + b2[j + i]) * mask[j + i]);
    oB[i] = (_Float16)(((hr[i] - mu) * rstd * w2[DIM + j + i] + b2[DIM + j + i]) * mask[DIM + j + i]);
  }
  *(f16x4*)&inp2[(size_t)row * TWO_D + j]       = oA;
  *(f16x4*)&inp2[(size_t)row * TWO_D + DIM + j] = oB;
}

// ---------------------------------------------------------------------------
// 256x256 GEMM, SQUARE-WAVE geometry: 256 threads = 4 waves in 2x2, each
// wave owns a 128x128 output (8x8 fragments of 16x16). LDS reads per K-tile
// drop 192KB -> 128KB (per-wave A+B slice = 16+16KB, only 4 waves), and at
// 1 wave/SIMD each wave overlaps its own ds_reads with MFMA (reads issue
// before the raw barrier; MFMAs consume with incremental lgkm waits).
// Schedule = R11 (best measured): 4 phases/tile, deep prefetch:
//   stA(t+1, both halves)@p1 (8 copies), stB(t+2, both halves)@p2 (8);
//   p4: vmcnt(8) leaves B(t+2) in flight, drains A(t+1)+B(t+1). Tail: 0.
//   Drains at p1 close (B reads vs p2's stB) and p4 close (cumulative).
// LDS: LA/LB = 2 buffers x 256x64 fp16 (128KB). XOR-chunk swizzle: slot c
// of row r holds global chunk c^(r&7); staging lane tid -> slot (tid&7),
// row (tid>>3)+32*seg (r&7 == (tid>>3)&7, seg-invariant); read chunk
// (ks*4+fq)^(r&7). 2-way bank aliasing = free.
// MODE 0: gates fp16 out (+bias).
// MODE 1: h_new = part16 + tanh(acc+bias)*z2, {part16,z2} packed u32 already
//         in outp (written by gate_ln2); same-thread read-then-overwrite.
// ---------------------------------------------------------------------------
template<int MODE>
__global__ __launch_bounds__(256, 1)
void gemm8p(const _Float16* __restrict__ A,
            const _Float16* __restrict__ Bw,
            const float* __restrict__ bias,
            void* __restrict__ outp,
            int M, int N, int K, int nbx, int total)
{
  __shared__ _Float16 LA[2 * 256 * 64];
  __shared__ _Float16 LB[2 * 256 * 64];

  const int lbid  = blockIdx.x + gridDim.x * blockIdx.y;
  const int chunk = total >> 3;
  const int swz   = (lbid & 7) * chunk + (lbid >> 3);
  const int bxi   = swz % nbx;
  const int byi   = swz / nbx;
  const int brow  = byi * 256;
  const int bcol  = bxi * 256;

  const int tid  = threadIdx.x;
  const int lane = tid & 63;
  const int w    = tid >> 6;      // 0..3
  const int wr   = w >> 1;        // 0..1 (M half)
  const int wc   = w & 1;         // 0..1 (N half)
  const int fr   = lane & 15;
  const int fq   = lane >> 4;
  const int gch  = (tid & 7) ^ ((tid >> 3) & 7);  // swizzled source chunk
  const int srw  = tid >> 3;      // staging row 0..31 (per 32-row segment)

  const int nt = K >> 6;          // even (K=1024 -> 16)

  auto stA = [&](int t2, int h) {
    const int b2 = t2 & 1;
    const _Float16* s = A + (size_t)(brow + h * 128 + srw) * K + t2 * 64 + gch * 8;
    char* d = (char*)LA + b2 * 32768 + h * 16384 + tid * 16;
    async_copy16(s,                    d);
    async_copy16(s + (size_t)32 * K,   d + 4096);
    async_copy16(s + (size_t)64 * K,   d + 8192);
    async_copy16(s + (size_t)96 * K,   d + 12288);
  };
  auto stB = [&](int t2, int h) {
    const int b2 = t2 & 1;
    const _Float16* s = Bw + (size_t)(bcol + h * 128 + srw) * K + t2 * 64 + gch * 8;
    char* d = (char*)LB + b2 * 32768 + h * 16384 + tid * 16;
    async_copy16(s,                    d);
    async_copy16(s + (size_t)32 * K,   d + 4096);
    async_copy16(s + (size_t)64 * K,   d + 8192);
    async_copy16(s + (size_t)96 * K,   d + 12288);
  };

  f16x8 af[2][2], bf[8][2];
  f32x4 acc[8][8];
#pragma unroll
  for (int m = 0; m < 8; ++m)
#pragma unroll
    for (int n = 0; n < 8; ++n)
      acc[m][n] = (f32x4){0.f, 0.f, 0.f, 0.f};

  auto rdA2 = [&](int b, int pair) {
#pragma unroll
    for (int j = 0; j < 2; ++j) {
      const int r = wr * 128 + (pair * 2 + j) * 16 + fr;
#pragma unroll
      for (int ks = 0; ks < 2; ++ks)
        af[j][ks] = *(const f16x8*)((const char*)LA + b * 32768 + r * 128 +
                                    (((ks * 4 + fq) ^ (fr & 7)) << 4));
    }
  };
  auto rdB_all = [&](int b) {
#pragma unroll
    for (int ni = 0; ni < 8; ++ni) {
      const int r = wc * 128 + ni * 16 + fr;
#pragma unroll
      for (int ks = 0; ks < 2; ++ks)
        bf[ni][ks] = *(const f16x8*)((const char*)LB + b * 32768 + r * 128 +
                                     (((ks * 4 + fq) ^ (fr & 7)) << 4));
    }
  };
  // ks-outer order: 16 distinct accumulators between reuses of the same acc.
  auto mf = [&](int p) {
#pragma unroll
    for (int ks = 0; ks < 2; ++ks)
#pragma unroll
      for (int j = 0; j < 2; ++j)
#pragma unroll
        for (int n = 0; n < 8; ++n)
          acc[2 * p + j][n] = __builtin_amdgcn_mfma_f32_16x16x32_f16(
              af[j][ks], bf[n][ks], acc[2 * p + j][n], 0, 0, 0);
  };

#define KTILE(T, BC)                                                         \
  {                                                                          \
    const int t = (T);                                                       \
    /* p1: reads (B all + A pair0) + deep A prefetch (t+1, both halves) */   \
    rdB_all(BC);                                                             \
    rdA2(BC, 0);                                                             \
    if (t + 1 < nt) { stA(t + 1, 0); stA(t + 1, 1); }                        \
    __builtin_amdgcn_s_barrier();                                            \
    __builtin_amdgcn_s_setprio(1);                                           \
    mf(0);                                                                   \
    __builtin_amdgcn_s_setprio(0);                                           \
    LGKM_DRAIN();                                                            \
    __builtin_amdgcn_s_barrier();                                            \
    /* p2: A pair1 + deep B prefetch (t+2, both halves) */                   \
    rdA2(BC, 1);                                                             \
    if (t + 2 < nt) { stB(t + 2, 0); stB(t + 2, 1); }                        \
    __builtin_amdgcn_s_barrier();                                            \
    __builtin_amdgcn_s_setprio(1);                                           \
    mf(1);                                                                   \
    __builtin_amdgcn_s_setprio(0);                                           \
    __builtin_amdgcn_s_barrier();                                            \
    /* p3 */                                                                 \
    rdA2(BC, 2);                                                             \
    __builtin_amdgcn_s_barrier();                                            \
    __builtin_amdgcn_s_setprio(1);                                           \
    mf(2);                                                                   \
    __builtin_amdgcn_s_setprio(0);                                           \
    __builtin_amdgcn_s_barrier();                                            \
    /* p4 */                                                                 \
    rdA2(BC, 3);                                                             \
    __builtin_amdgcn_s_barrier();                                            \
    __builtin_amdgcn_s_setprio(1);                                           \
    mf(3);                                                                   \
    __builtin_amdgcn_s_setprio(0);                                           \
    if (t + 2 < nt) { asm volatile("s_waitcnt vmcnt(8)" ::: "memory"); }     \
    else            { asm volatile("s_waitcnt vmcnt(0)" ::: "memory"); }     \
    LGKM_DRAIN();                                                            \
    __builtin_amdgcn_s_barrier();                                            \
  }

  // prologue: tile 0 fully, then B halves of tile 1; leave B(1) in flight.
  stA(0, 0); stA(0, 1); stB(0, 0); stB(0, 1);
  if (nt > 1) { stB(1, 0); stB(1, 1); }
  if (nt > 1) { asm volatile("s_waitcnt vmcnt(8)" ::: "memory"); }
  else        { asm volatile("s_waitcnt vmcnt(0)" ::: "memory"); }
  __builtin_amdgcn_s_barrier();

  for (int tt = 0; tt < nt; tt += 2) {
    KTILE(tt, 0);
    KTILE(tt + 1, 1);
  }
#undef KTILE

  if (MODE == 0) {
    _Float16* Co = (_Float16*)outp;
#pragma unroll
    for (int m = 0; m < 8; ++m) {
#pragma unroll
      for (int n = 0; n < 8; ++n) {
        const int col = bcol + wc * 128 + n * 16 + fr;
        const float bv = bias[col];
#pragma unroll
        for (int jj = 0; jj < 4; ++jj) {
          const int row = brow + wr * 128 + m * 16 + fq * 4 + jj;
          Co[(size_t)row * N + col] = (_Float16)(acc[m][n][jj] + bv);
        }
      }
    }
  } else {
    float*    Co  = (float*)outp;
    uint32_t* pzp = (uint32_t*)outp;
#pragma unroll
    for (int m = 0; m < 8; ++m) {
#pragma unroll
      for (int n = 0; n < 8; ++n) {
        const int col = bcol + wc * 128 + n * 16 + fr;
        const float bv = bias[col];
#pragma unroll
        for (int jj = 0; jj < 4; ++jj) {
          const int row = brow + wr * 128 + m * 16 + fq * 4 + jj;
          const size_t idx = (size_t)row * DIM + col;
          const uint32_t pz = pzp[idx];
          const float p  = (float)__builtin_bit_cast(_Float16, (uint16_t)(pz & 0xFFFFu));
          const float z2 = (float)__builtin_bit_cast(_Float16, (uint16_t)(pz >> 16));
          const float u  = tanhf(acc[m][n][jj] + bv);
          Co[idx] = p + u * z2;
        }
      }
    }
  }
}

// ---------------------------------------------------------------------------
// launch
// ---------------------------------------------------------------------------
extern "C" void kernel_launch(void* const* d_in, const int* in_sizes, int n_in,
                              void* d_out, int out_size, void* d_ws, size_t ws_size,
                              hipStream_t stream)
{
  const float* x    = (const float*)d_in[0];
  const float* h    = (const float*)d_in[1];
  const float* Wg   = (const float*)d_in[2];
  const float* bg   = (const float*)d_in[3];
  const float* Wu   = (const float*)d_in[4];
  const float* bu   = (const float*)d_in[5];
  const float* lnw  = (const float*)d_in[6];
  const float* lnb  = (const float*)d_in[7];
  const float* ln2w = (const float*)d_in[8];
  const float* ln2b = (const float*)d_in[9];
  const float* mask = (const float*)d_in[10];

  // ws layout (bytes):
  //   [0,            5242880)   Wg fp16  [2560*1024]
  //   [5242880,      6291456)   Wu fp16  [512*1024]
  //   [6291456,     73400320)   inp fp16 [32768*1024]   (reused as inp2)
  //   [73400320,   241172480)   gates fp16 [32768*2560]
  // d_out doubles as the packed {part16,z2} buffer between gate_ln2 and
  // GEMM2 (same-thread read-then-overwrite in GEMM2's epilogue).
  char* ws = (char*)d_ws;
  _Float16* wg16  = (_Float16*)(ws);
  _Float16* wu16  = (_Float16*)(ws + 5242880);
  _Float16* inp16 = (_Float16*)(ws + 6291456);
  _Float16* gates = (_Float16*)(ws + 73400320);

  cvt_kernel<<<2560, 256, 0, stream>>>(Wg, wg16, FIVE_D * TWO_D / 4);
  cvt_kernel<<<512, 256, 0, stream>>>(Wu, wu16, DIM * TWO_D / 4);

  ln1_kernel<<<BATCH, 256, 0, stream>>>(x, h, lnw, lnb, mask, inp16);

  gemm8p<0><<<dim3(FIVE_D / 256, BATCH / 256), 256, 0, stream>>>(
      inp16, wg16, bg, (void*)gates,
      BATCH, FIVE_D, TWO_D, FIVE_D / 256, (FIVE_D / 256) * (BATCH / 256));

  gate_ln2_kernel<<<BATCH, 128, 0, stream>>>(x, h, gates, ln2w, ln2b, mask,
                                             inp16, (uint32_t*)d_out);

  gemm8p<1><<<dim3(DIM / 256, BATCH / 256), 256, 0, stream>>>(
      inp16, wu16, bu, d_out,
      BATCH, DIM, TWO_D, DIM / 256, (DIM / 256) * (BATCH / 256));
}

// Round 15
// 384.651 us; speedup vs baseline: 1.1723x; 1.1723x over previous
//
#include <hip/hip_runtime.h>
#include <hip/hip_bf16.h>
#include <stdint.h>

// Problem constants (DGRUCell: DIM=512, BATCH=32768)
#define DIM      512
#define TWO_D    1024
#define FIVE_D   2560
#define BATCH    32768
#define LN_EPS   1e-5f
#define GATE_B   0.0f

typedef _Float16 f16x8 __attribute__((ext_vector_type(8)));
typedef _Float16 f16x4 __attribute__((ext_vector_type(4)));
typedef float    f32x4 __attribute__((ext_vector_type(4)));

// ---------------------------------------------------------------------------
// async global->LDS, 16B per lane. LDS dest = wave-uniform base + lane*16.
// ---------------------------------------------------------------------------
__device__ __forceinline__ void async_copy16(const void* g, void* l) {
  __builtin_amdgcn_global_load_lds(
      (const __attribute__((address_space(1))) uint32_t*)g,
      (__attribute__((address_space(3))) uint32_t*)l,
      16, 0, 0);
}

// Drain: all this wave's outstanding LDS reads must be DATA-complete before
// it may cross the following barrier (after which another wave's
// global_load_lds may overwrite the region).
#define LGKM_DRAIN() asm volatile("s_waitcnt lgkmcnt(0)" ::: "memory")

__device__ __forceinline__ uint32_t pack_pz(_Float16 p, _Float16 z) {
  return (uint32_t)__builtin_bit_cast(uint16_t, p) |
         ((uint32_t)__builtin_bit_cast(uint16_t, z) << 16);
}

// ---------------------------------------------------------------------------
// K0: fp32 -> fp16 conversion of BOTH weight matrices in one launch.
// wg16 (2560*1024) and wu16 (512*1024) are contiguous in ws; index < nWg
// sources Wg, else Wu.
// ---------------------------------------------------------------------------
__global__ __launch_bounds__(256)
void cvt2_kernel(const float* __restrict__ Wg, const float* __restrict__ Wu,
                 _Float16* __restrict__ d, int nWg4, int n4) {
  int i = blockIdx.x * blockDim.x + threadIdx.x;
  if (i < n4) {
    const float* s = (i < nWg4) ? (Wg + (size_t)i * 4)
                                : (Wu + (size_t)(i - nWg4) * 4);
    float4 v = *(const float4*)s;
    f16x4 o;
    o[0] = (_Float16)v.x; o[1] = (_Float16)v.y;
    o[2] = (_Float16)v.z; o[3] = (_Float16)v.w;
    *(f16x4*)&d[(size_t)i * 4] = o;
  }
}

// ---------------------------------------------------------------------------
// K1: LN1 over concat(x,h) -> inp fp16 [B, 1024]
// ---------------------------------------------------------------------------
__global__ __launch_bounds__(256)
void ln1_kernel(const float* __restrict__ x, const float* __restrict__ h,
                const float* __restrict__ w, const float* __restrict__ b,
                const float* __restrict__ mask, _Float16* __restrict__ inp)
{
  const int row = blockIdx.x;
  const int t   = threadIdx.x;
  const int col = t * 4;
  const float* src = (col < DIM) ? (x + (size_t)row * DIM + col)
                                 : (h + (size_t)row * DIM + (col - DIM));
  float4 v = *(const float4*)src;
  float s = v.x + v.y + v.z + v.w;
  float q = v.x * v.x + v.y * v.y + v.z * v.z + v.w * v.w;
#pragma unroll
  for (int o = 32; o > 0; o >>= 1) { s += __shfl_xor(s, o); q += __shfl_xor(q, o); }
  __shared__ float red[8];
  const int wid = t >> 6;
  if ((t & 63) == 0) { red[wid] = s; red[4 + wid] = q; }
  __syncthreads();
  s = red[0] + red[1] + red[2] + red[3];
  q = red[4] + red[5] + red[6] + red[7];
  const float mu   = s * (1.0f / TWO_D);
  const float rstd = rsqrtf(q * (1.0f / TWO_D) - mu * mu + LN_EPS);
  float vv[4] = { v.x, v.y, v.z, v.w };
  f16x4 o4;
#pragma unroll
  for (int i = 0; i < 4; ++i)
    o4[i] = (_Float16)(((vv[i] - mu) * rstd * w[col + i] + b[col + i]) * mask[col + i]);
  *(f16x4*)&inp[(size_t)row * TWO_D + col] = o4;
}

// ---------------------------------------------------------------------------
// K3: gate nonlinearities + LN2. Writes inp2 (fp16) and the packed
// {part16, z2} u32 per output element COALESCED into d_out (GEMM2 reads it
// and overwrites the same element with h_new — same-thread read-then-write).
// ---------------------------------------------------------------------------
__global__ __launch_bounds__(128)
void gate_ln2_kernel(const float* __restrict__ x, const float* __restrict__ h,
                     const _Float16* __restrict__ gates,
                     const float* __restrict__ w2, const float* __restrict__ b2,
                     const float* __restrict__ mask, _Float16* __restrict__ inp2,
                     uint32_t* __restrict__ pz_out)
{
  const int row = blockIdx.x;
  const int t   = threadIdx.x;
  const int j   = t * 4;
  const _Float16* g = gates + (size_t)row * FIVE_D;

  f16x4 g0 = *(const f16x4*)&g[j];
  f16x4 g1 = *(const f16x4*)&g[DIM + j];
  f16x4 g2 = *(const f16x4*)&g[2 * DIM + j];
  f16x4 g3 = *(const f16x4*)&g[3 * DIM + j];
  f16x4 g4 = *(const f16x4*)&g[4 * DIM + j];
  float4 xv = *(const float4*)(x + (size_t)row * DIM + j);
  float4 hv = *(const float4*)(h + (size_t)row * DIM + j);
  float xa[4] = { xv.x, xv.y, xv.z, xv.w };
  float ha[4] = { hv.x, hv.y, hv.z, hv.w };

  float xr[4], hr[4];
  uint4 pzv;
  uint32_t pza[4];
  float s = 0.f, q = 0.f;
#pragma unroll
  for (int i = 0; i < 4; ++i) {
    float rx = 1.0f / (1.0f + expf(-(float)g0[i]));
    float rh = 1.0f / (1.0f + expf(-(float)g1[i]));
    xr[i] = xa[i] * rx;
    hr[i] = ha[i] * rh;
    float a = (float)g2[i], bb = (float)g3[i], c = (float)g4[i] - GATE_B;
    float m = fmaxf(fmaxf(a, bb), c);
    float e0 = expf(a - m), e1 = expf(bb - m), e2 = expf(c - m);
    float inv = 1.0f / (e0 + e1 + e2);
    float z0 = e0 * inv, z1 = e1 * inv;
    pza[i] = pack_pz((_Float16)(xa[i] * z0 + ha[i] * z1), (_Float16)(e2 * inv));
    s += xr[i] + hr[i];
    q += xr[i] * xr[i] + hr[i] * hr[i];
  }
  pzv.x = pza[0]; pzv.y = pza[1]; pzv.z = pza[2]; pzv.w = pza[3];
  *(uint4*)&pz_out[(size_t)row * DIM + j] = pzv;

#pragma unroll
  for (int o = 32; o > 0; o >>= 1) { s += __shfl_xor(s, o); q += __shfl_xor(q, o); }
  __shared__ float red[4];
  const int wid = t >> 6;
  if ((t & 63) == 0) { red[wid] = s; red[2 + wid] = q; }
  __syncthreads();
  s = red[0] + red[1];
  q = red[2] + red[3];
  const float mu   = s * (1.0f / TWO_D);
  const float rstd = rsqrtf(q * (1.0f / TWO_D) - mu * mu + LN_EPS);

  f16x4 oA, oB;
#pragma unroll
  for (int i = 0; i < 4; ++i) {
    oA[i] = (_Float16)(((xr[i] - mu) * rstd * w2[j + i] + b2[j + i]) * mask[j + i]);
    oB[i] = (_Float16)(((hr[i] - mu) * rstd * w2[DIM + j + i] + b2[DIM + j + i]) * mask[DIM + j + i]);
  }
  *(f16x4*)&inp2[(size_t)row * TWO_D + j]       = oA;
  *(f16x4*)&inp2[(size_t)row * TWO_D + DIM + j] = oB;
}

// ---------------------------------------------------------------------------
// 8-phase 256x256 GEMM (R11/R13 best-measured: deep prefetch, counted vmcnt).
// BK=64, 512 threads = 8 waves (2M x 4N), per-wave 128x64.
// LDS: LA/LB = 2 buffers x 256x64 fp16 (128KB). XOR-chunk swizzle (same
// involution on staging source and ds_read; 2-way aliasing = free).
//   stA(t+1, both halves) @p1 (target LA[BC^1], drained t-1 p4); drained at
//   p4 vmcnt(4). stB(t+2, both halves) @p2 (target LB[BC], read-drained at
//   p1 close); drained at NEXT tile's p4. Tail: vmcnt(0).
// MODE 0: gates fp16 out (+bias).
// MODE 1: h_new = part16 + tanh(acc+bias)*z2 where {part16,z2} is the packed
//         u32 ALREADY IN outp (written coalesced by gate_ln2); same-thread
//         read-then-overwrite, fp32 out.
// ---------------------------------------------------------------------------
template<int MODE>
__global__ __launch_bounds__(512, 2)
void gemm8p(const _Float16* __restrict__ A,
            const _Float16* __restrict__ Bw,
            const float* __restrict__ bias,
            void* __restrict__ outp,
            int M, int N, int K, int nbx, int total)
{
  __shared__ _Float16 LA[2 * 256 * 64];
  __shared__ _Float16 LB[2 * 256 * 64];

  const int lbid  = blockIdx.x + gridDim.x * blockIdx.y;
  const int chunk = total >> 3;
  const int swz   = (lbid & 7) * chunk + (lbid >> 3);
  const int bxi   = swz % nbx;
  const int byi   = swz / nbx;
  const int brow  = byi * 256;
  const int bcol  = bxi * 256;

  const int tid  = threadIdx.x;
  const int lane = tid & 63;
  const int w    = tid >> 6;      // 0..7
  const int wr   = w >> 2;        // 0..1 (M half)
  const int wc   = w & 3;         // 0..3 (N quarter)
  const int fr   = lane & 15;
  const int fq   = lane >> 4;
  const int gch  = (tid & 7) ^ ((tid >> 3) & 7);  // swizzled source chunk
  const int srw  = tid >> 3;      // staging row 0..63

  const int nt = K >> 6;          // even (K=1024 -> 16)

  auto stA = [&](int t2, int h) {
    const int b2 = t2 & 1;
    const _Float16* s = A + (size_t)(brow + h * 128 + srw) * K + t2 * 64 + gch * 8;
    char* d = (char*)LA + b2 * 32768 + h * 16384 + tid * 16;
    async_copy16(s, d);
    async_copy16(s + (size_t)64 * K, d + 8192);
  };
  auto stB = [&](int t2, int h) {
    const int b2 = t2 & 1;
    const _Float16* s = Bw + (size_t)(bcol + h * 128 + srw) * K + t2 * 64 + gch * 8;
    char* d = (char*)LB + b2 * 32768 + h * 16384 + tid * 16;
    async_copy16(s, d);
    async_copy16(s + (size_t)64 * K, d + 8192);
  };

  f16x8 af[2][2], bf[4][2];
  f32x4 acc[8][4];
#pragma unroll
  for (int m = 0; m < 8; ++m)
#pragma unroll
    for (int n = 0; n < 4; ++n)
      acc[m][n] = (f32x4){0.f, 0.f, 0.f, 0.f};

  auto rdA2 = [&](int b, int pair) {
#pragma unroll
    for (int j = 0; j < 2; ++j) {
      const int r = wr * 128 + (pair * 2 + j) * 16 + fr;
#pragma unroll
      for (int ks = 0; ks < 2; ++ks)
        af[j][ks] = *(const f16x8*)((const char*)LA + b * 32768 + r * 128 +
                                    (((ks * 4 + fq) ^ (fr & 7)) << 4));
    }
  };
  auto rdB_all = [&](int b) {
#pragma unroll
    for (int ni = 0; ni < 4; ++ni) {
      const int r = wc * 64 + ni * 16 + fr;
#pragma unroll
      for (int ks = 0; ks < 2; ++ks)
        bf[ni][ks] = *(const f16x8*)((const char*)LB + b * 32768 + r * 128 +
                                     (((ks * 4 + fq) ^ (fr & 7)) << 4));
    }
  };
  auto mf = [&](int p) {
#pragma unroll
    for (int j = 0; j < 2; ++j)
#pragma unroll
      for (int n = 0; n < 4; ++n) {
        acc[2 * p + j][n] = __builtin_amdgcn_mfma_f32_16x16x32_f16(af[j][0], bf[n][0], acc[2 * p + j][n], 0, 0, 0);
        acc[2 * p + j][n] = __builtin_amdgcn_mfma_f32_16x16x32_f16(af[j][1], bf[n][1], acc[2 * p + j][n], 0, 0, 0);
      }
  };

#define KTILE(T, BC)                                                         \
  {                                                                          \
    const int t = (T);                                                       \
    /* p1: reads + deep A prefetch (t+1, both halves) */                     \
    rdB_all(BC);                                                             \
    rdA2(BC, 0);                                                             \
    if (t + 1 < nt) { stA(t + 1, 0); stA(t + 1, 1); }                        \
    __builtin_amdgcn_s_barrier();                                            \
    __builtin_amdgcn_s_setprio(1);                                           \
    mf(0);                                                                   \
    __builtin_amdgcn_s_setprio(0);                                           \
    LGKM_DRAIN();                                                            \
    __builtin_amdgcn_s_barrier();                                            \
    /* p2: reads + deep B prefetch (t+2, both halves) */                     \
    rdA2(BC, 1);                                                             \
    if (t + 2 < nt) { stB(t + 2, 0); stB(t + 2, 1); }                        \
    __builtin_amdgcn_s_barrier();                                            \
    __builtin_amdgcn_s_setprio(1);                                           \
    mf(1);                                                                   \
    __builtin_amdgcn_s_setprio(0);                                           \
    __builtin_amdgcn_s_barrier();                                            \
    /* p3 */                                                                 \
    rdA2(BC, 2);                                                             \
    __builtin_amdgcn_s_barrier();                                            \
    __builtin_amdgcn_s_setprio(1);                                           \
    mf(2);                                                                   \
    __builtin_amdgcn_s_setprio(0);                                           \
    __builtin_amdgcn_s_barrier();                                            \
    /* p4 */                                                                 \
    rdA2(BC, 3);                                                             \
    __builtin_amdgcn_s_barrier();                                            \
    __builtin_amdgcn_s_setprio(1);                                           \
    mf(3);                                                                   \
    __builtin_amdgcn_s_setprio(0);                                           \
    if (t + 2 < nt) { asm volatile("s_waitcnt vmcnt(4)" ::: "memory"); }     \
    else            { asm volatile("s_waitcnt vmcnt(0)" ::: "memory"); }     \
    LGKM_DRAIN();                                                            \
    __builtin_amdgcn_s_barrier();                                            \
  }

  // prologue: tile 0 fully, then B halves of tile 1; leave B(1) in flight.
  stA(0, 0); stA(0, 1); stB(0, 0); stB(0, 1);
  if (nt > 1) { stB(1, 0); stB(1, 1); }
  if (nt > 1) { asm volatile("s_waitcnt vmcnt(4)" ::: "memory"); }
  else        { asm volatile("s_waitcnt vmcnt(0)" ::: "memory"); }
  __builtin_amdgcn_s_barrier();

  for (int tt = 0; tt < nt; tt += 2) {
    KTILE(tt, 0);
    KTILE(tt + 1, 1);
  }
#undef KTILE

  if (MODE == 0) {
    _Float16* Co = (_Float16*)outp;
#pragma unroll
    for (int m = 0; m < 8; ++m) {
#pragma unroll
      for (int n = 0; n < 4; ++n) {
        const int col = bcol + wc * 64 + n * 16 + fr;
        const float bv = bias[col];
#pragma unroll
        for (int jj = 0; jj < 4; ++jj) {
          const int row = brow + wr * 128 + m * 16 + fq * 4 + jj;
          Co[(size_t)row * N + col] = (_Float16)(acc[m][n][jj] + bv);
        }
      }
    }
  } else {
    float*    Co  = (float*)outp;
    uint32_t* pzp = (uint32_t*)outp;
#pragma unroll
    for (int m = 0; m < 8; ++m) {
#pragma unroll
      for (int n = 0; n < 4; ++n) {
        const int col = bcol + wc * 64 + n * 16 + fr;
        const float bv = bias[col];
#pragma unroll
        for (int jj = 0; jj < 4; ++jj) {
          const int row = brow + wr * 128 + m * 16 + fq * 4 + jj;
          const size_t idx = (size_t)row * DIM + col;
          const uint32_t pz = pzp[idx];
          const float p  = (float)__builtin_bit_cast(_Float16, (uint16_t)(pz & 0xFFFFu));
          const float z2 = (float)__builtin_bit_cast(_Float16, (uint16_t)(pz >> 16));
          const float u  = tanhf(acc[m][n][jj] + bv);
          Co[idx] = p + u * z2;
        }
      }
    }
  }
}

// ---------------------------------------------------------------------------
// launch
// ---------------------------------------------------------------------------
extern "C" void kernel_launch(void* const* d_in, const int* in_sizes, int n_in,
                              void* d_out, int out_size, void* d_ws, size_t ws_size,
                              hipStream_t stream)
{
  const float* x    = (const float*)d_in[0];
  const float* h    = (const float*)d_in[1];
  const float* Wg   = (const float*)d_in[2];
  const float* bg   = (const float*)d_in[3];
  const float* Wu   = (const float*)d_in[4];
  const float* bu   = (const float*)d_in[5];
  const float* lnw  = (const float*)d_in[6];
  const float* lnb  = (const float*)d_in[7];
  const float* ln2w = (const float*)d_in[8];
  const float* ln2b = (const float*)d_in[9];
  const float* mask = (const float*)d_in[10];

  // ws layout (bytes):
  //   [0,            5242880)   Wg fp16  [2560*1024]
  //   [5242880,      6291456)   Wu fp16  [512*1024]   (contiguous with Wg)
  //   [6291456,     73400320)   inp fp16 [32768*1024]  (reused as inp2)
  //   [73400320,   241172480)   gates fp16 [32768*2560]
  // d_out doubles as the packed {part16,z2} buffer between gate_ln2 and
  // GEMM2 (same-thread read-then-overwrite in GEMM2's epilogue).
  char* ws = (char*)d_ws;
  _Float16* wg16  = (_Float16*)(ws);
  _Float16* wu16  = (_Float16*)(ws + 5242880);
  _Float16* inp16 = (_Float16*)(ws + 6291456);
  _Float16* gates = (_Float16*)(ws + 73400320);

  const int nWg4 = FIVE_D * TWO_D / 4;
  const int nAll4 = (FIVE_D + DIM) * TWO_D / 4;
  cvt2_kernel<<<(nAll4 + 255) / 256, 256, 0, stream>>>(Wg, Wu, wg16, nWg4, nAll4);

  ln1_kernel<<<BATCH, 256, 0, stream>>>(x, h, lnw, lnb, mask, inp16);

  gemm8p<0><<<dim3(FIVE_D / 256, BATCH / 256), 512, 0, stream>>>(
      inp16, wg16, bg, (void*)gates,
      BATCH, FIVE_D, TWO_D, FIVE_D / 256, (FIVE_D / 256) * (BATCH / 256));

  gate_ln2_kernel<<<BATCH, 128, 0, stream>>>(x, h, gates, ln2w, ln2b, mask,
                                             inp16, (uint32_t*)d_out);

  gemm8p<1><<<dim3(DIM / 256, BATCH / 256), 512, 0, stream>>>(
      inp16, wu16, bu, d_out,
      BATCH, DIM, TWO_D, DIM / 256, (DIM / 256) * (BATCH / 256));
}